// Round 3
// baseline (360.270 us; speedup 1.0000x reference)
//
#include <hip/hip_runtime.h>
#include <hip/hip_cooperative_groups.h>

namespace cg = cooperative_groups;

#define K_CLUST 1024

typedef int v4i __attribute__((ext_vector_type(4)));

// One fused cooperative kernel:
//   phase 0: zero presence flags (d_ws isn't re-poisoned between replays)
//   phase 1: presence sweep over labels (LDS flags -> idempotent global store)
//   phase 2: stable double-argsort rank -> mapping[1024]
//   phase 3: relabel gather, nontemporal int4 stores (don't evict labels from L3)
__global__ __launch_bounds__(256, 8)
void fused_kernel(const int* __restrict__ labels,
                  const float* __restrict__ peak,
                  int* __restrict__ out, int n,
                  int* __restrict__ flags,
                  int* __restrict__ mapping) {
    cg::grid_group grid = cg::this_grid();
    __shared__ float smem[K_CLUST];   // reused: byte flags / aa floats / int lmap
    __shared__ int partial[4];

    const int t = threadIdx.x;
    const int gtid = blockIdx.x * blockDim.x + t;
    const int gstride = gridDim.x * blockDim.x;
    const int n4 = n >> 2;
    const v4i* l4 = (const v4i*)labels;

    // ---- Phase 0: zero global flags ----
    for (int c = gtid; c < K_CLUST; c += gstride) flags[c] = 0;
    grid.sync();

    // ---- Phase 1: presence sweep ----
    unsigned char* lflag = (unsigned char*)smem;
    for (int c = t; c < K_CLUST; c += blockDim.x) lflag[c] = 0;
    __syncthreads();

    for (int i = gtid; i < n4; i += gstride) {
        v4i v = l4[i];
        lflag[(v.x - 1) & (K_CLUST - 1)] = 1;
        lflag[(v.y - 1) & (K_CLUST - 1)] = 1;
        lflag[(v.z - 1) & (K_CLUST - 1)] = 1;
        lflag[(v.w - 1) & (K_CLUST - 1)] = 1;
    }
    for (int i = (n4 << 2) + gtid; i < n; i += gstride)
        lflag[(labels[i] - 1) & (K_CLUST - 1)] = 1;
    __syncthreads();
    for (int c = t; c < K_CLUST; c += blockDim.x)
        if (lflag[c]) flags[c] = 1;
    grid.sync();

    // ---- Phase 2: rank. rank[i] = #{j: aa[j]<aa[i]} + #{j<i: aa[j]==aa[i]} ----
    // Empty clusters get +inf; inf==inf ties break by index (stable argsort).
    float* aa = smem;
    for (int c = t; c < K_CLUST; c += blockDim.x)
        aa[c] = flags[c] ? peak[c] : __builtin_huge_valf();
    __syncthreads();
    for (int i = blockIdx.x; i < K_CLUST; i += gridDim.x) {
        const float mine = aa[i];
        int cnt = 0;
        #pragma unroll
        for (int r = 0; r < K_CLUST / 256; ++r) {
            int j = t + r * 256;
            float v = aa[j];
            cnt += (v < mine) || (v == mine && j < i);
        }
        #pragma unroll
        for (int off = 32; off > 0; off >>= 1)
            cnt += __shfl_down(cnt, off, 64);
        if ((t & 63) == 0) partial[t >> 6] = cnt;
        __syncthreads();
        if (t == 0)
            mapping[i] = partial[0] + partial[1] + partial[2] + partial[3] + 1;
        __syncthreads();  // partial[] reused next iteration
    }
    grid.sync();

    // ---- Phase 3: relabel gather, nt stores ----
    int* lmap = (int*)smem;
    for (int c = t; c < K_CLUST; c += blockDim.x) lmap[c] = mapping[c];
    __syncthreads();
    v4i* o4 = (v4i*)out;
    for (int i = gtid; i < n4; i += gstride) {
        v4i v = l4[i];
        v4i r;
        r.x = lmap[(v.x - 1) & (K_CLUST - 1)];
        r.y = lmap[(v.y - 1) & (K_CLUST - 1)];
        r.z = lmap[(v.z - 1) & (K_CLUST - 1)];
        r.w = lmap[(v.w - 1) & (K_CLUST - 1)];
        __builtin_nontemporal_store(r, &o4[i]);
    }
    for (int i = (n4 << 2) + gtid; i < n; i += gstride)
        out[i] = lmap[(labels[i] - 1) & (K_CLUST - 1)];
}

// ------- fallback split kernels (used only if cooperative launch fails) -------
__global__ void flags_kernel(const int* __restrict__ labels, int n,
                             int* __restrict__ flags) {
    __shared__ unsigned char lflag[K_CLUST];
    for (int c = threadIdx.x; c < K_CLUST; c += blockDim.x) lflag[c] = 0;
    __syncthreads();
    const int n4 = n >> 2;
    const v4i* l4 = (const v4i*)labels;
    int idx = blockIdx.x * blockDim.x + threadIdx.x;
    int stride = gridDim.x * blockDim.x;
    for (int i = idx; i < n4; i += stride) {
        v4i v = l4[i];
        lflag[(v.x - 1) & (K_CLUST - 1)] = 1;
        lflag[(v.y - 1) & (K_CLUST - 1)] = 1;
        lflag[(v.z - 1) & (K_CLUST - 1)] = 1;
        lflag[(v.w - 1) & (K_CLUST - 1)] = 1;
    }
    for (int i = (n4 << 2) + idx; i < n; i += stride)
        lflag[(labels[i] - 1) & (K_CLUST - 1)] = 1;
    __syncthreads();
    for (int c = threadIdx.x; c < K_CLUST; c += blockDim.x)
        if (lflag[c]) flags[c] = 1;
}

__global__ void rank_kernel(const float* __restrict__ peak,
                            const int* __restrict__ flags,
                            int* __restrict__ mapping) {
    __shared__ float aa[K_CLUST];
    __shared__ int partial[4];
    const int t = threadIdx.x;
    for (int c = t; c < K_CLUST; c += 256)
        aa[c] = flags[c] ? peak[c] : __builtin_huge_valf();
    __syncthreads();
    const int i = blockIdx.x;
    const float mine = aa[i];
    int cnt = 0;
    #pragma unroll
    for (int r = 0; r < K_CLUST / 256; ++r) {
        int j = t + r * 256;
        float v = aa[j];
        cnt += (v < mine) || (v == mine && j < i);
    }
    #pragma unroll
    for (int off = 32; off > 0; off >>= 1)
        cnt += __shfl_down(cnt, off, 64);
    if ((t & 63) == 0) partial[t >> 6] = cnt;
    __syncthreads();
    if (t == 0)
        mapping[i] = partial[0] + partial[1] + partial[2] + partial[3] + 1;
}

__global__ void relabel_kernel(const int* __restrict__ labels,
                               const int* __restrict__ mapping,
                               int* __restrict__ out, int n) {
    __shared__ int lmap[K_CLUST];
    for (int c = threadIdx.x; c < K_CLUST; c += blockDim.x) lmap[c] = mapping[c];
    __syncthreads();
    const int n4 = n >> 2;
    const v4i* l4 = (const v4i*)labels;
    v4i* o4 = (v4i*)out;
    int idx = blockIdx.x * blockDim.x + threadIdx.x;
    int stride = gridDim.x * blockDim.x;
    for (int i = idx; i < n4; i += stride) {
        v4i v = l4[i];
        v4i r;
        r.x = lmap[(v.x - 1) & (K_CLUST - 1)];
        r.y = lmap[(v.y - 1) & (K_CLUST - 1)];
        r.z = lmap[(v.z - 1) & (K_CLUST - 1)];
        r.w = lmap[(v.w - 1) & (K_CLUST - 1)];
        __builtin_nontemporal_store(r, &o4[i]);
    }
    for (int i = (n4 << 2) + idx; i < n; i += stride)
        out[i] = lmap[(labels[i] - 1) & (K_CLUST - 1)];
}

extern "C" void kernel_launch(void* const* d_in, const int* in_sizes, int n_in,
                              void* d_out, int out_size, void* d_ws, size_t ws_size,
                              hipStream_t stream) {
    const int*   labels = (const int*)d_in[0];
    const float* peak   = (const float*)d_in[1];
    int n = in_sizes[0];

    int* flags   = (int*)d_ws;            // K_CLUST ints
    int* mapping = flags + K_CLUST;       // K_CLUST ints
    int* out     = (int*)d_out;

    // Co-residency sizing for the cooperative launch (deterministic host query).
    int maxb = 0;
    hipOccupancyMaxActiveBlocksPerMultiprocessor(&maxb, (const void*)fused_kernel, 256, 0);
    if (maxb < 1) maxb = 1;
    int blocks = maxb * 256;              // 256 CUs
    if (blocks > 2048) blocks = 2048;

    void* args[] = {(void*)&labels, (void*)&peak, (void*)&out, (void*)&n,
                    (void*)&flags, (void*)&mapping};
    hipError_t err = hipLaunchCooperativeKernel((const void*)fused_kernel,
                                                dim3(blocks), dim3(256),
                                                args, 0, stream);
    if (err != hipSuccess) {
        // Fallback: split pipeline (4 dispatches).
        hipMemsetAsync(flags, 0, K_CLUST * sizeof(int), stream);
        flags_kernel<<<2048, 256, 0, stream>>>(labels, n, flags);
        rank_kernel<<<K_CLUST, 256, 0, stream>>>(peak, flags, mapping);
        relabel_kernel<<<2048, 256, 0, stream>>>(labels, mapping, out, n);
    }
}

// Round 4
// 46.932 us; speedup vs baseline: 7.6764x; 7.6764x over previous
//
#include <hip/hip_runtime.h>

#define K_CLUST 1024

typedef int v4i __attribute__((ext_vector_type(4)));

// Pass 1: per-block LDS presence flags over labels, then one idempotent
// global store per present cluster. No atomics needed (store of 1 races benignly).
__global__ void flags_kernel(const int* __restrict__ labels, int n,
                             int* __restrict__ flags) {
    __shared__ unsigned char lflag[K_CLUST];
    for (int c = threadIdx.x; c < K_CLUST; c += blockDim.x) lflag[c] = 0;
    __syncthreads();

    const int n4 = n >> 2;
    const v4i* l4 = (const v4i*)labels;
    int idx = blockIdx.x * blockDim.x + threadIdx.x;
    int stride = gridDim.x * blockDim.x;
    for (int i = idx; i < n4; i += stride) {
        v4i v = l4[i];
        lflag[(v.x - 1) & (K_CLUST - 1)] = 1;
        lflag[(v.y - 1) & (K_CLUST - 1)] = 1;
        lflag[(v.z - 1) & (K_CLUST - 1)] = 1;
        lflag[(v.w - 1) & (K_CLUST - 1)] = 1;
    }
    for (int i = (n4 << 2) + idx; i < n; i += stride)
        lflag[(labels[i] - 1) & (K_CLUST - 1)] = 1;

    __syncthreads();
    for (int c = threadIdx.x; c < K_CLUST; c += blockDim.x)
        if (lflag[c]) flags[c] = 1;
}

// Pass 2: stable double-argsort rank. One block PER cluster i (1024 blocks x
// 256 threads). rank[i] = #{j: aa[j]<aa[i]} + #{j<i: aa[j]==aa[i]}; map=rank+1.
// Empty clusters get +inf; inf==inf ties break by index (stable argsort).
__global__ void rank_kernel(const float* __restrict__ peak,
                            const int* __restrict__ flags,
                            int* __restrict__ mapping) {
    __shared__ float aa[K_CLUST];
    __shared__ int partial[4];
    const int t = threadIdx.x;
    for (int c = t; c < K_CLUST; c += 256)
        aa[c] = flags[c] ? peak[c] : __builtin_huge_valf();
    __syncthreads();

    const int i = blockIdx.x;
    const float mine = aa[i];
    int cnt = 0;
    #pragma unroll
    for (int r = 0; r < K_CLUST / 256; ++r) {
        int j = t + r * 256;
        float v = aa[j];
        cnt += (v < mine) || (v == mine && j < i);
    }
    #pragma unroll
    for (int off = 32; off > 0; off >>= 1)
        cnt += __shfl_down(cnt, off, 64);
    if ((t & 63) == 0) partial[t >> 6] = cnt;
    __syncthreads();
    if (t == 0)
        mapping[i] = partial[0] + partial[1] + partial[2] + partial[3] + 1;
}

// Pass 3: gather mapping[label-1] for every spike. int4 loads; NONTEMPORAL
// int4 stores — output is write-once, nt keeps it from evicting labels
// from L2/L3 (labels stay cache-warm from pass 1 / across replays).
__global__ void relabel_kernel(const int* __restrict__ labels,
                               const int* __restrict__ mapping,
                               int* __restrict__ out, int n) {
    __shared__ int lmap[K_CLUST];
    for (int c = threadIdx.x; c < K_CLUST; c += blockDim.x) lmap[c] = mapping[c];
    __syncthreads();

    const int n4 = n >> 2;
    const v4i* l4 = (const v4i*)labels;
    v4i* o4 = (v4i*)out;
    int idx = blockIdx.x * blockDim.x + threadIdx.x;
    int stride = gridDim.x * blockDim.x;
    for (int i = idx; i < n4; i += stride) {
        v4i v = l4[i];
        v4i r;
        r.x = lmap[(v.x - 1) & (K_CLUST - 1)];
        r.y = lmap[(v.y - 1) & (K_CLUST - 1)];
        r.z = lmap[(v.z - 1) & (K_CLUST - 1)];
        r.w = lmap[(v.w - 1) & (K_CLUST - 1)];
        __builtin_nontemporal_store(r, &o4[i]);
    }
    for (int i = (n4 << 2) + idx; i < n; i += stride)
        out[i] = lmap[(labels[i] - 1) & (K_CLUST - 1)];
}

extern "C" void kernel_launch(void* const* d_in, const int* in_sizes, int n_in,
                              void* d_out, int out_size, void* d_ws, size_t ws_size,
                              hipStream_t stream) {
    const int*   labels = (const int*)d_in[0];
    const float* peak   = (const float*)d_in[1];
    const int n = in_sizes[0];

    int* flags   = (int*)d_ws;            // K_CLUST ints
    int* mapping = flags + K_CLUST;       // K_CLUST ints

    // d_ws is poisoned 0xAA once and never re-poisoned; flags must start at 0
    // every call. hipMemsetAsync on the stream is graph-capture safe.
    hipMemsetAsync(flags, 0, K_CLUST * sizeof(int), stream);

    const int threads = 256;
    const int blocks  = 2048;  // 256 CUs x 8 blocks, grid-stride covers the rest

    flags_kernel<<<blocks, threads, 0, stream>>>(labels, n, flags);
    rank_kernel<<<K_CLUST, 256, 0, stream>>>(peak, flags, mapping);
    relabel_kernel<<<blocks, threads, 0, stream>>>(labels, mapping, (int*)d_out, n);
}